// Round 7
// baseline (101.672 us; speedup 1.0000x reference)
//
#include <hip/hip_runtime.h>
#include <math.h>

#define BB 4
#define NN 1024
#define DIN 128
#define DOUT 64
#define SLOPE 0.01f
#define CAP 256  // per-row edge capacity (nnz ~52±7; P(>256) ~ 0)

// ws layout: [0, 2 MB) = x12 (B*N*128 fp32); then lwP[64][128] (32 KB):
// lwP[k2*128 + d*2 + r] = lin_w[d*128 + 2*k2 + r]  (k-paired, d-major inner)

// Kernel 1: wave-per-row projection, grid 4096 rows + 8 lwP-transpose blocks.
__global__ __launch_bounds__(64, 8) void proj_kernel(
    const float* __restrict__ x, const float* __restrict__ w1,
    const float* __restrict__ w2, const float* __restrict__ lin_w,
    float* __restrict__ x12, float* __restrict__ lwP) {
  int l = threadIdx.x;
  if (blockIdx.x >= BB * NN) {
    // build paired-transposed lin_w; 8 blocks x 1024 elems, coalesced writes
    int base = (blockIdx.x - BB * NN) * 1024;
#pragma unroll
    for (int i = 0; i < 16; ++i) {
      int idx = base + i * 64 + l;        // flat over lwP
      int k2 = idx >> 7;
      int rem = idx & 127;
      int d = rem >> 1, r = rem & 1;
      lwP[idx] = lin_w[d * DIN + 2 * k2 + r];
    }
    return;
  }
  int row = blockIdx.x;
  __shared__ __align__(16) float xl[DIN];
  reinterpret_cast<float2*>(xl)[l] =
      reinterpret_cast<const float2*>(x + (size_t)row * DIN)[l];
  __syncthreads();
  const float* w1c = w1 + l;
  const float* w2c = w2 + l;
  float a1 = 0.f, a2 = 0.f;
#pragma unroll 8
  for (int k = 0; k < DIN; ++k) {
    float xv = xl[k];                     // LDS broadcast
    a1 = fmaf(xv, w1c[k * DOUT], a1);     // coalesced 256B, L1-hot
    a2 = fmaf(xv, w2c[k * DOUT], a2);
  }
  x12[(size_t)row * 128 + l] = a1;
  x12[(size_t)row * 128 + DOUT + l] = a2;
}

__device__ __forceinline__ float fast_edge_exp(float sc) {
  // e = exp(8*tanh(sc/8)); tanh via exp, clamped so __expf stays finite
  float z = sc * 0.125f;
  z = fminf(10.f, fmaxf(-10.f, z));
  float u = __expf(2.f * z);
  float th = (u - 1.f) / (u + 1.f);
  return __expf(8.f * th);
}

// Kernel 2: each WAVE owns one (b,i) row end-to-end; 2 independent waves per
// 128-thr block (separate LDS slices, NO block barriers), grid 2048 ->
// 32 waves/CU. Score+aggregate fused per edge: 4 edges/iter across 16-lane
// groups; e computed redundantly in all 16 lanes; acc normalized at end.
__global__ __launch_bounds__(128, 8) void gat_row_kernel(
    const float* __restrict__ x, const float* __restrict__ A_shape,
    const float* __restrict__ a_vec, const float* __restrict__ lwP,
    const float* __restrict__ x12, float* __restrict__ out) {
  int tid = threadIdx.x;
  int w = tid >> 6;
  int lane = tid & 63;
  int bi = blockIdx.x * 2 + w;  // this wave's row
  int b = bi >> 10;

  __shared__ int eidx_s[2][CAP];
  __shared__ __align__(16) float agg_s[2][DIN];
  int* eidx = eidx_s[w];
  float* aggw = agg_s[w];

  // ---- Phase A: ballot-compact this row's mask (16 coalesced 256B loads) ----
  const float* mask_row = A_shape + (size_t)bi * NN;
  float mv[16];
#pragma unroll
  for (int c = 0; c < 16; ++c) mv[c] = mask_row[c * 64 + lane];
  int base = 0;
#pragma unroll
  for (int c = 0; c < 16; ++c) {
    bool pred = (mv[c] != 0.f);
    unsigned long long m = __ballot(pred);
    int prefix = __popcll(m & ((1ull << lane) - 1ull));
    int slot = base + prefix;
    if (pred && slot < CAP) eidx[slot] = c * 64 + lane;
    base += __popcll(m);  // wave-uniform
  }
  int nz = base < CAP ? base : CAP;

  // ---- Fused score+aggregate: 16-lane group g handles edge s+g ----
  int l16 = lane & 15;
  int grp = lane >> 4;
  float4 x1v = *reinterpret_cast<const float4*>(x12 + (size_t)bi * 128 + l16 * 4);
  float4 avv = *reinterpret_cast<const float4*>(a_vec + l16 * 4);
  const float* x2b = x12 + (size_t)b * NN * 128 + DOUT;  // x2 half, stride 128
  const float* xb = x + (size_t)b * NN * DIN;
  float acc[8] = {0.f, 0.f, 0.f, 0.f, 0.f, 0.f, 0.f, 0.f};
  float esum = 0.f;
  for (int s = 0; s < nz; s += 4) {
    int sg = s + grp;
    bool valid = sg < nz;
    int j = eidx[valid ? sg : nz - 1];    // LDS (4 distinct addrs/wave)
    const float* x2r = x2b + (size_t)j * 128;
    const float* xr = xb + (size_t)j * DIN;
    // three independent coalesced gathers per group: 256B + 2x256B
    float4 x2v = *reinterpret_cast<const float4*>(x2r + l16 * 4);
    float4 xa = *reinterpret_cast<const float4*>(xr + l16 * 8);
    float4 xc = *reinterpret_cast<const float4*>(xr + l16 * 8 + 4);
    float z, sc = 0.f;
    z = x1v.x + x2v.x; sc = fmaf(z >= 0.f ? z : SLOPE * z, avv.x, sc);
    z = x1v.y + x2v.y; sc = fmaf(z >= 0.f ? z : SLOPE * z, avv.y, sc);
    z = x1v.z + x2v.z; sc = fmaf(z >= 0.f ? z : SLOPE * z, avv.z, sc);
    z = x1v.w + x2v.w; sc = fmaf(z >= 0.f ? z : SLOPE * z, avv.w, sc);
    sc += __shfl_xor(sc, 1, 64);
    sc += __shfl_xor(sc, 2, 64);
    sc += __shfl_xor(sc, 4, 64);
    sc += __shfl_xor(sc, 8, 64);         // all 16 lanes now hold the score
    float e = valid ? fast_edge_exp(sc) : 0.f;  // redundant in 16 lanes
    esum += e;
    acc[0] = fmaf(e, xa.x, acc[0]);
    acc[1] = fmaf(e, xa.y, acc[1]);
    acc[2] = fmaf(e, xa.z, acc[2]);
    acc[3] = fmaf(e, xa.w, acc[3]);
    acc[4] = fmaf(e, xc.x, acc[4]);
    acc[5] = fmaf(e, xc.y, acc[5]);
    acc[6] = fmaf(e, xc.z, acc[6]);
    acc[7] = fmaf(e, xc.w, acc[7]);
  }
  // cross-group reduction (esum is uniform within each group)
  esum += __shfl_xor(esum, 16, 64);
  esum += __shfl_xor(esum, 32, 64);
  float inv = 1.f / esum;
#pragma unroll
  for (int r = 0; r < 8; ++r) {
    acc[r] += __shfl_xor(acc[r], 16, 64);
    acc[r] += __shfl_xor(acc[r], 32, 64);
    acc[r] *= inv;
  }
  if (grp == 0) {  // lanes 0..15 write agg[128]: 2 float4 LDS writes each
    float4 lo = {acc[0], acc[1], acc[2], acc[3]};
    float4 hi = {acc[4], acc[5], acc[6], acc[7]};
    *reinterpret_cast<float4*>(aggw + l16 * 8) = lo;
    *reinterpret_cast<float4*>(aggw + l16 * 8 + 4) = hi;
  }
  __builtin_amdgcn_wave_barrier();  // ordering hint; lgkmcnt dependence holds

  // ---- Epilogue: out[d] = lrelu(sum_k agg[k]*lin_w[d,k]) via paired lwP ----
  float o = 0.f;
#pragma unroll 8
  for (int k2 = 0; k2 < 64; ++k2) {
    float2 ag = *reinterpret_cast<const float2*>(aggw + k2 * 2);   // broadcast
    float2 lw = *reinterpret_cast<const float2*>(lwP + k2 * 128 + lane * 2);
    o = fmaf(ag.y, lw.y, fmaf(ag.x, lw.x, o));
  }
  o = o >= 0.f ? o : SLOPE * o;
  out[(size_t)bi * DOUT + lane] = o;
}

extern "C" void kernel_launch(void* const* d_in, const int* in_sizes, int n_in,
                              void* d_out, int out_size, void* d_ws, size_t ws_size,
                              hipStream_t stream) {
  const float* x = (const float*)d_in[0];
  const float* A_shape = (const float*)d_in[1];
  const float* w1 = (const float*)d_in[2];
  const float* w2 = (const float*)d_in[3];
  const float* a = (const float*)d_in[4];
  const float* lin_w = (const float*)d_in[5];
  float* out = (float*)d_out;
  float* x12 = (float*)d_ws;                          // 2 MB
  float* lwP = (float*)d_ws + (size_t)BB * NN * 128;  // 32 KB

  proj_kernel<<<BB * NN + 8, 64, 0, stream>>>(x, w1, w2, lin_w, x12, lwP);
  gat_row_kernel<<<BB * NN / 2, 128, 0, stream>>>(x, A_shape, a, lwP, x12, out);
}